// Round 1
// baseline (3662.955 us; speedup 1.0000x reference)
//
#include <hip/hip_runtime.h>
#include <hip/hip_bf16.h>
#include <math.h>

#define B_SZ 2
#define SEQLEN 2048
#define D_MODEL 1024
#define D_INNER 2048
#define D_STATE 16
#define D_CONV 4
#define DT_RANK 64
#define NTOK (B_SZ * SEQLEN)      /* 4096 */
#define XDBL 96                   /* DT_RANK + 2*D_STATE */

__device__ __forceinline__ float siluf(float v) { return v / (1.f + expf(-v)); }
__device__ __forceinline__ float softplusf(float v) { return (v > 20.f) ? v : log1pf(expf(v)); }

// ---- expert-gathered GEMM: out[t][o] = sum_k act[t][k] * W[ids[t]][o][k]
// 64 tokens x 64 outs per block; 256 threads; each thread 4x4 micro-tile.
template <int KDIM, int NOUT, bool SPLIT>
__global__ __launch_bounds__(256) void k_gemm(const float* __restrict__ act,
                                              const int* __restrict__ ids,
                                              const float* __restrict__ W,
                                              float* __restrict__ out0,
                                              float* __restrict__ out1) {
  constexpr int KB = 16;
  const int ot = blockIdx.x * 64;
  const int tt = blockIdx.y * 64;
  const int tid = threadIdx.x;
  const int tl = (tid & 15) * 4;   // local token base
  const int ol = (tid >> 4) * 4;   // local out base
  __shared__ float As[KB][64];
  __shared__ float Ws[2][KB][64];
  float acc[4][4] = {};
  int eid[4];
#pragma unroll
  for (int i = 0; i < 4; i++) eid[i] = ids[tt + tl + i];

  for (int k0 = 0; k0 < KDIM; k0 += KB) {
#pragma unroll
    for (int q = 0; q < 4; q++) {  // 64 tok x 16 k = 1024 floats
      int idx = tid * 4 + q;
      int t = idx >> 4, kk = idx & 15;
      As[kk][t] = act[(size_t)(tt + t) * KDIM + k0 + kk];
    }
#pragma unroll
    for (int q = 0; q < 8; q++) {  // 2 experts x 64 outs x 16 k = 2048 floats
      int idx = tid * 8 + q;
      int e = idx >> 10, r = idx & 1023, o = r >> 4, kk = r & 15;
      Ws[e][kk][o] = W[((size_t)e * NOUT + ot + o) * KDIM + k0 + kk];
    }
    __syncthreads();
#pragma unroll
    for (int kk = 0; kk < KB; kk++) {
      float a[4];
#pragma unroll
      for (int i = 0; i < 4; i++) a[i] = As[kk][tl + i];
#pragma unroll
      for (int i = 0; i < 4; i++) {
        const float* w = &Ws[eid[i]][kk][ol];
#pragma unroll
        for (int j = 0; j < 4; j++) acc[i][j] = fmaf(a[i], w[j], acc[i][j]);
      }
    }
    __syncthreads();
  }

#pragma unroll
  for (int i = 0; i < 4; i++) {
    const size_t t = (size_t)(tt + tl + i);
#pragma unroll
    for (int j = 0; j < 4; j++) {
      int o = ot + ol + j;
      if (SPLIT) {
        if (o < D_INNER)
          out0[t * D_INNER + o] = acc[i][j];
        else
          out1[t * D_INNER + (o - D_INNER)] = acc[i][j];
      } else {
        out0[t * NOUT + o] = acc[i][j];
      }
    }
  }
}

// ---- depthwise causal conv (4 taps along L) + SiLU; token-major layout
__global__ __launch_bounds__(256) void k_conv(const float* __restrict__ x_raw,
                                              const float* __restrict__ cw,
                                              const float* __restrict__ cb,
                                              float* __restrict__ x_act) {
  int idx = blockIdx.x * 256 + threadIdx.x;  // over NTOK*D_INNER
  int c = idx & (D_INNER - 1);
  int t = idx >> 11;
  int l = t & (SEQLEN - 1);
  int b = t >> 11;
  float acc = cb[c];
#pragma unroll
  for (int k = 0; k < D_CONV; k++) {
    int ll = l + k - (D_CONV - 1);
    if (ll >= 0)
      acc = fmaf(cw[c * D_CONV + k], x_raw[((size_t)(b * SEQLEN + ll)) * D_INNER + c], acc);
  }
  x_act[(size_t)idx] = siluf(acc);
}

// ---- x_dbl[t][0..95] = W_x[id]·x_act[t]; one block per token
__global__ __launch_bounds__(128) void k_xdbl(const float* __restrict__ x_act,
                                              const int* __restrict__ ids,
                                              const float* __restrict__ Wx,
                                              float* __restrict__ xdbl) {
  __shared__ float xs[D_INNER];
  const int t = blockIdx.x;
  const int tid = threadIdx.x;
#pragma unroll
  for (int q = 0; q < D_INNER / 128; q++)
    xs[q * 128 + tid] = x_act[(size_t)t * D_INNER + q * 128 + tid];
  __syncthreads();
  if (tid < XDBL) {
    const int e = ids[t];
    const float4* w4 = (const float4*)(Wx + ((size_t)e * XDBL + tid) * D_INNER);
    const float4* xs4 = (const float4*)xs;
    float acc = 0.f;
    for (int k = 0; k < D_INNER / 4; k++) {
      float4 w = w4[k], x = xs4[k];
      acc += w.x * x.x + w.y * x.y + w.z * x.z + w.w * x.w;
    }
    xdbl[(size_t)t * XDBL + tid] = acc;
  }
}

// ---- dt[t][c] = softplus(W_dt[id]·x_dbl[t][0:64] + b_dt[id][c]); block per token
__global__ __launch_bounds__(256) void k_dt(const float* __restrict__ xdbl,
                                            const int* __restrict__ ids,
                                            const float* __restrict__ Wdt,
                                            const float* __restrict__ bdt,
                                            float* __restrict__ dtb) {
  __shared__ float s[DT_RANK];
  const int t = blockIdx.x;
  const int tid = threadIdx.x;
  if (tid < DT_RANK) s[tid] = xdbl[(size_t)t * XDBL + tid];
  __syncthreads();
  const int e = ids[t];
#pragma unroll
  for (int q = 0; q < D_INNER / 256; q++) {
    int c = q * 256 + tid;
    const float4* w4 = (const float4*)(Wdt + ((size_t)e * D_INNER + c) * DT_RANK);
    const float4* s4 = (const float4*)s;
    float acc = 0.f;
#pragma unroll
    for (int k = 0; k < DT_RANK / 4; k++) {
      float4 w = w4[k], x = s4[k];
      acc += w.x * x.x + w.y * x.y + w.z * x.z + w.w * x.w;
    }
    acc += bdt[e * D_INNER + c];
    dtb[(size_t)t * D_INNER + c] = softplusf(acc);
  }
}

// ---- selective scan: 16 lanes per (b,c) channel, one lane per state n.
// Fused epilogue: y = (scan + x*D) * silu(z)
__global__ __launch_bounds__(256) void k_scan(const float* __restrict__ x_act,
                                              const float* __restrict__ dtb,
                                              const float* __restrict__ xdbl,
                                              const float* __restrict__ z_buf,
                                              const float* __restrict__ A_log,
                                              const float* __restrict__ Dp,
                                              float* __restrict__ ybuf) {
  const int tid = threadIdx.x;
  const int b = blockIdx.x >> 7;
  const int c = ((blockIdx.x & 127) << 4) + (tid >> 4);
  const int n = tid & 15;
  const float Ac = -expf(A_log[c * D_STATE + n]);
  const float Dc = Dp[c];
  float st = 0.f;
  const size_t tok0 = (size_t)b * SEQLEN;
  float dtv = dtb[tok0 * D_INNER + c];
  float xv = x_act[tok0 * D_INNER + c];
  float Bv = xdbl[tok0 * XDBL + DT_RANK + n];
  float Cv = xdbl[tok0 * XDBL + DT_RANK + D_STATE + n];
  for (int l = 0; l < SEQLEN; ++l) {
    float dt_n = 0.f, x_n = 0.f, B_n = 0.f, C_n = 0.f;
    if (l + 1 < SEQLEN) {  // prefetch next step
      size_t t2 = tok0 + l + 1;
      dt_n = dtb[t2 * D_INNER + c];
      x_n = x_act[t2 * D_INNER + c];
      B_n = xdbl[t2 * XDBL + DT_RANK + n];
      C_n = xdbl[t2 * XDBL + DT_RANK + D_STATE + n];
    }
    float dA = expf(dtv * Ac);
    st = fmaf(st, dA, dtv * xv * Bv);
    float p = st * Cv;
    p += __shfl_xor(p, 1);
    p += __shfl_xor(p, 2);
    p += __shfl_xor(p, 4);
    p += __shfl_xor(p, 8);
    if (n == 0) {
      size_t t = tok0 + l;
      float yv = fmaf(xv, Dc, p);
      float zv = z_buf[t * D_INNER + c];
      yv *= zv / (1.f + expf(-zv));
      ybuf[t * D_INNER + c] = yv;
    }
    dtv = dt_n; xv = x_n; Bv = B_n; Cv = C_n;
  }
}

extern "C" void kernel_launch(void* const* d_in, const int* in_sizes, int n_in,
                              void* d_out, int out_size, void* d_ws, size_t ws_size,
                              hipStream_t stream) {
  const float* h = (const float*)d_in[0];
  const int* ids = (const int*)d_in[1];
  const float* Win = (const float*)d_in[2];
  const float* cw = (const float*)d_in[3];
  const float* cb = (const float*)d_in[4];
  const float* Wx = (const float*)d_in[5];
  const float* Wdt = (const float*)d_in[6];
  const float* bdt = (const float*)d_in[7];
  const float* Alog = (const float*)d_in[8];
  const float* Dp = (const float*)d_in[9];
  const float* Wout = (const float*)d_in[10];
  float* out = (float*)d_out;

  const size_t NTD = (size_t)NTOK * D_INNER;  // 8,388,608 floats
  float* ws = (float*)d_ws;
  float* x_act = ws;            // post conv+silu x, token-major
  float* z_buf = ws + NTD;      // z, token-major
  float* dtb_p = ws + 2 * NTD;  // softplus(dt)
  float* y_p = ws + 3 * NTD;    // pre-conv x, later overwritten by y
  float* xdbl_p = ws + 4 * NTD; // NTOK*96
  float* x_raw = y_p;           // alias: pre-conv x is dead after k_conv

  k_gemm<D_MODEL, 2 * D_INNER, true><<<dim3(64, 64), 256, 0, stream>>>(h, ids, Win, x_raw, z_buf);
  k_conv<<<NTD / 256, 256, 0, stream>>>(x_raw, cw, cb, x_act);
  k_xdbl<<<NTOK, 128, 0, stream>>>(x_act, ids, Wx, xdbl_p);
  k_dt<<<NTOK, 256, 0, stream>>>(xdbl_p, ids, Wdt, bdt, dtb_p);
  k_scan<<<256, 256, 0, stream>>>(x_act, dtb_p, xdbl_p, z_buf, Alog, Dp, y_p);
  k_gemm<D_INNER, D_MODEL, false><<<dim3(16, 64), 256, 0, stream>>>(y_p, ids, Wout, out, nullptr);
}

// Round 2
// 2015.619 us; speedup vs baseline: 1.8173x; 1.8173x over previous
//
#include <hip/hip_runtime.h>
#include <hip/hip_bf16.h>
#include <math.h>

#define B_SZ 2
#define SEQLEN 2048
#define D_MODEL 1024
#define D_INNER 2048
#define D_STATE 16
#define D_CONV 4
#define DT_RANK 64
#define NTOK (B_SZ * SEQLEN)      /* 4096 */
#define XDBL 96                   /* DT_RANK + 2*D_STATE */
#define NC 32                     /* scan chunks */
#define LC 64                     /* chunk length */

__device__ __forceinline__ float siluf(float v) { return v / (1.f + __expf(-v)); }
__device__ __forceinline__ float softplusf(float v) { return (v > 20.f) ? v : log1pf(__expf(v)); }

// ---- token partition by expert: perm = [tokens with id==0 (stable), tokens with id==1]
__global__ __launch_bounds__(1024) void k_perm(const int* __restrict__ ids, int* __restrict__ perm) {
  __shared__ int sc[1024];
  const int tid = threadIdx.x;
  int loc[4];
  int cnt = 0;
#pragma unroll
  for (int q = 0; q < 4; q++) {
    loc[q] = ids[tid * 4 + q];
    cnt += (loc[q] == 0);
  }
  sc[tid] = cnt;
  __syncthreads();
  for (int off = 1; off < 1024; off <<= 1) {
    int v = sc[tid];
    int u = (tid >= off) ? sc[tid - off] : 0;
    __syncthreads();
    sc[tid] = v + u;
    __syncthreads();
  }
  const int N0 = sc[1023];
  int zb = sc[tid] - cnt;  // zeros before this thread's segment
#pragma unroll
  for (int q = 0; q < 4; q++) {
    int t = tid * 4 + q;
    if (loc[q] == 0) { perm[zb] = t; zb++; }
    else             { perm[N0 + (t - zb)] = t; }
  }
}

// ---- expert-gathered GEMM, 128x128 tile, 8x8 micro-tile, sorted rows via perm.
// EPI 0: plain store out0[t*LDO+o]
// EPI 1: split: o<D_INNER -> out0 (x), else out1 (z)
// EPI 2: softplus(acc + bias[e*NW+o]) -> out0
template <int KDIM, int LDA, int NW, int LDO, int EPI>
__global__ __launch_bounds__(256) void k_gemmT(const float* __restrict__ act,
                                               const int* __restrict__ perm,
                                               const int* __restrict__ ids,
                                               const float* __restrict__ W,
                                               const float* __restrict__ bias,
                                               float* __restrict__ out0,
                                               float* __restrict__ out1) {
  __shared__ float As[16][128];
  __shared__ float Ws[2][16][128];
  __shared__ int permL[128];
  __shared__ int eidL[128];
  const int tid = threadIdx.x;
  const int ot = blockIdx.x * 128;
  const int tt = blockIdx.y * 128;
  if (tid < 128) {
    int t = perm[tt + tid];
    permL[tid] = t;
    eidL[tid] = ids[t];
  }
  __syncthreads();
  const bool mixed = (eidL[0] != eidL[127]);
  const int eu = eidL[0];
  const int tx4 = (tid & 15) * 4;
  const int ty4 = (tid >> 4) * 4;
  float acc[8][8] = {};
  bool bsel[8];
  if (mixed) {
#pragma unroll
    for (int i = 0; i < 8; i++) {
      int m = (i < 4) ? (ty4 + i) : (64 + ty4 + i - 4);
      bsel[i] = (eidL[m] != eu);
    }
  }

  for (int k0 = 0; k0 < KDIM; k0 += 16) {
#pragma unroll
    for (int v2 = 0; v2 < 2; v2++) {  // stage A: 128 tok x 16 k
      const int ci = tid * 2 + v2;
      const int m = ci >> 2, ks = (ci & 3) * 4;
      const float4 f = *(const float4*)&act[(size_t)permL[m] * LDA + k0 + ks];
      As[ks + 0][m] = f.x; As[ks + 1][m] = f.y; As[ks + 2][m] = f.z; As[ks + 3][m] = f.w;
    }
#pragma unroll
    for (int v2 = 0; v2 < 2; v2++) {  // stage W (expert eu)
      const int ci = tid * 2 + v2;
      const int o = ci >> 2, ks = (ci & 3) * 4;
      int orow = ot + o;
      if (NW % 128 != 0) orow = (orow < NW) ? orow : (NW - 1);
      const float4 f = *(const float4*)&W[((size_t)eu * NW + orow) * KDIM + k0 + ks];
      Ws[0][ks + 0][o] = f.x; Ws[0][ks + 1][o] = f.y; Ws[0][ks + 2][o] = f.z; Ws[0][ks + 3][o] = f.w;
    }
    if (mixed) {
#pragma unroll
      for (int v2 = 0; v2 < 2; v2++) {  // stage W (other expert)
        const int ci = tid * 2 + v2;
        const int o = ci >> 2, ks = (ci & 3) * 4;
        int orow = ot + o;
        if (NW % 128 != 0) orow = (orow < NW) ? orow : (NW - 1);
        const float4 f = *(const float4*)&W[((size_t)(1 - eu) * NW + orow) * KDIM + k0 + ks];
        Ws[1][ks + 0][o] = f.x; Ws[1][ks + 1][o] = f.y; Ws[1][ks + 2][o] = f.z; Ws[1][ks + 3][o] = f.w;
      }
    }
    __syncthreads();
    if (!mixed) {
#pragma unroll
      for (int kk = 0; kk < 16; kk++) {
        const float4 a0 = *(const float4*)&As[kk][ty4];
        const float4 a1 = *(const float4*)&As[kk][64 + ty4];
        const float4 w0 = *(const float4*)&Ws[0][kk][tx4];
        const float4 w1 = *(const float4*)&Ws[0][kk][64 + tx4];
        const float av[8] = {a0.x, a0.y, a0.z, a0.w, a1.x, a1.y, a1.z, a1.w};
        const float wv[8] = {w0.x, w0.y, w0.z, w0.w, w1.x, w1.y, w1.z, w1.w};
#pragma unroll
        for (int i = 0; i < 8; i++)
#pragma unroll
          for (int jj = 0; jj < 8; jj++)
            acc[i][jj] = fmaf(av[i], wv[jj], acc[i][jj]);
      }
    } else {
#pragma unroll
      for (int kk = 0; kk < 16; kk++) {
        const float4 a0 = *(const float4*)&As[kk][ty4];
        const float4 a1 = *(const float4*)&As[kk][64 + ty4];
        const float4 u0 = *(const float4*)&Ws[0][kk][tx4];
        const float4 u1 = *(const float4*)&Ws[0][kk][64 + tx4];
        const float4 q0 = *(const float4*)&Ws[1][kk][tx4];
        const float4 q1 = *(const float4*)&Ws[1][kk][64 + tx4];
        const float av[8] = {a0.x, a0.y, a0.z, a0.w, a1.x, a1.y, a1.z, a1.w};
        const float we0[8] = {u0.x, u0.y, u0.z, u0.w, u1.x, u1.y, u1.z, u1.w};
        const float we1[8] = {q0.x, q0.y, q0.z, q0.w, q1.x, q1.y, q1.z, q1.w};
#pragma unroll
        for (int i = 0; i < 8; i++)
#pragma unroll
          for (int jj = 0; jj < 8; jj++)
            acc[i][jj] = fmaf(av[i], bsel[i] ? we1[jj] : we0[jj], acc[i][jj]);
      }
    }
    __syncthreads();
  }

#pragma unroll
  for (int i = 0; i < 8; i++) {
    const int m = (i < 4) ? (ty4 + i) : (64 + ty4 + i - 4);
    const int t = permL[m];
    float v[8];
#pragma unroll
    for (int jj = 0; jj < 8; jj++) v[jj] = acc[i][jj];
    if (EPI == 2) {
      const int e = eidL[m];
#pragma unroll
      for (int jj = 0; jj < 8; jj++) {
        const int o = ot + ((jj < 4) ? (tx4 + jj) : (64 + tx4 + jj - 4));
        v[jj] = softplusf(v[jj] + bias[e * NW + o]);
      }
    }
    if (EPI == 1) {
      float* base = (ot < D_INNER) ? out0 : out1;
      const int col = (ot < D_INNER) ? ot : (ot - D_INNER);
      *(float4*)&base[(size_t)t * D_INNER + col + tx4] = make_float4(v[0], v[1], v[2], v[3]);
      *(float4*)&base[(size_t)t * D_INNER + col + 64 + tx4] = make_float4(v[4], v[5], v[6], v[7]);
    } else if (NW % 128 != 0) {
#pragma unroll
      for (int jj = 0; jj < 8; jj++) {
        const int o = ot + ((jj < 4) ? (tx4 + jj) : (64 + tx4 + jj - 4));
        if (o < NW) out0[(size_t)t * LDO + o] = v[jj];
      }
    } else {
      *(float4*)&out0[(size_t)t * LDO + ot + tx4] = make_float4(v[0], v[1], v[2], v[3]);
      *(float4*)&out0[(size_t)t * LDO + ot + 64 + tx4] = make_float4(v[4], v[5], v[6], v[7]);
    }
  }
}

// ---- depthwise causal conv (4 taps along L) + SiLU; token-major layout
__global__ __launch_bounds__(256) void k_conv(const float* __restrict__ x_raw,
                                              const float* __restrict__ cw,
                                              const float* __restrict__ cb,
                                              float* __restrict__ x_act) {
  int idx = blockIdx.x * 256 + threadIdx.x;  // over NTOK*D_INNER
  int c = idx & (D_INNER - 1);
  int t = idx >> 11;
  int l = t & (SEQLEN - 1);
  int b = t >> 11;
  float acc = cb[c];
#pragma unroll
  for (int k = 0; k < D_CONV; k++) {
    int ll = l + k - (D_CONV - 1);
    if (ll >= 0)
      acc = fmaf(cw[c * D_CONV + k], x_raw[((size_t)(b * SEQLEN + ll)) * D_INNER + c], acc);
  }
  x_act[(size_t)idx] = siluf(acc);
}

// ---- x_dbl = W_x[id]*x_act; 4 tokens per block to amortize W reads
__global__ __launch_bounds__(512) void k_xdbl(const float* __restrict__ x_act,
                                              const int* __restrict__ ids,
                                              const float* __restrict__ Wx,
                                              float* __restrict__ xdbl) {
  __shared__ float xs[4][D_INNER];
  const int sub = threadIdx.x >> 7;   // 0..3
  const int lt = threadIdx.x & 127;   // 0..127
  const int t = blockIdx.x * 4 + sub;
#pragma unroll
  for (int q = 0; q < D_INNER / 128; q++)
    xs[sub][q * 128 + lt] = x_act[(size_t)t * D_INNER + q * 128 + lt];
  __syncthreads();
  if (lt < XDBL) {
    const int e = ids[t];
    const float4* w4 = (const float4*)(Wx + ((size_t)e * XDBL + lt) * D_INNER);
    const float4* x4 = (const float4*)xs[sub];
    float acc = 0.f;
    for (int k = 0; k < D_INNER / 4; k++) {
      float4 w = w4[k], x = x4[k];
      acc += w.x * x.x + w.y * x.y + w.z * x.z + w.w * x.w;
    }
    xdbl[(size_t)t * XDBL + lt] = acc;
  }
}

// ---- scan pass A: per-chunk local scan -> F (final local state), Sdt (sum dt)
// lane = one (b,c) channel, 16 states in registers; B tile in LDS (broadcast).
__global__ __launch_bounds__(256) void k_scan_part(const float* __restrict__ x_act,
                                                   const float* __restrict__ dtb,
                                                   const float* __restrict__ xdbl,
                                                   const float* __restrict__ A_log,
                                                   float* __restrict__ F,
                                                   float* __restrict__ Sdt) {
  __shared__ float Bs[LC][D_STATE];
  const int tid = threadIdx.x;
  const int j = blockIdx.y;
  const int ch = blockIdx.x * 256 + tid;
  const int b = ch >> 11, c = ch & (D_INNER - 1);
  const int t0 = (b << 11) + j * LC;
  {
    int l = tid >> 2, q = (tid & 3) * 4;
    *(float4*)&Bs[l][q] = *(const float4*)&xdbl[(size_t)(t0 + l) * XDBL + DT_RANK + q];
  }
  float Ar[D_STATE];
#pragma unroll
  for (int n4 = 0; n4 < 4; n4++) {
    float4 a = *(const float4*)&A_log[(size_t)c * D_STATE + n4 * 4];
    Ar[n4 * 4 + 0] = -__expf(a.x); Ar[n4 * 4 + 1] = -__expf(a.y);
    Ar[n4 * 4 + 2] = -__expf(a.z); Ar[n4 * 4 + 3] = -__expf(a.w);
  }
  __syncthreads();
  float st[D_STATE];
#pragma unroll
  for (int n = 0; n < D_STATE; n++) st[n] = 0.f;
  float sdt = 0.f;
  float dtc = dtb[(size_t)t0 * D_INNER + c];
  float xc = x_act[(size_t)t0 * D_INNER + c];
  for (int l = 0; l < LC; l++) {
    float dtn = 0.f, xn = 0.f;
    if (l < LC - 1) {
      dtn = dtb[(size_t)(t0 + l + 1) * D_INNER + c];
      xn = x_act[(size_t)(t0 + l + 1) * D_INNER + c];
    }
    const float dtx = dtc * xc;
    sdt += dtc;
#pragma unroll
    for (int n = 0; n < D_STATE; n++) {
      float dA = __expf(dtc * Ar[n]);
      st[n] = fmaf(st[n], dA, dtx * Bs[l][n]);
    }
    dtc = dtn; xc = xn;
  }
  const size_t fb = ((size_t)j * NTOK + ch) * D_STATE;
#pragma unroll
  for (int n4 = 0; n4 < 4; n4++)
    *(float4*)&F[fb + n4 * 4] = make_float4(st[n4 * 4], st[n4 * 4 + 1], st[n4 * 4 + 2], st[n4 * 4 + 3]);
  Sdt[(size_t)j * NTOK + ch] = sdt;
}

// ---- scan pass B: sequential combine across chunks -> s0 per chunk
__global__ __launch_bounds__(256) void k_combine(const float* __restrict__ F,
                                                 const float* __restrict__ Sdt,
                                                 const float* __restrict__ A_log,
                                                 float* __restrict__ s0) {
  const int gid = blockIdx.x * 256 + threadIdx.x;  // 65536
  const int ch = gid >> 4, n = gid & 15, c = ch & (D_INNER - 1);
  const float Ar = -__expf(A_log[(size_t)c * D_STATE + n]);
  float s = 0.f;
  for (int j = 0; j < NC; j++) {
    s0[((size_t)j * NTOK + ch) * D_STATE + n] = s;
    s = fmaf(s, __expf(Ar * Sdt[(size_t)j * NTOK + ch]), F[((size_t)j * NTOK + ch) * D_STATE + n]);
  }
}

// ---- scan pass C: recompute with correct s0, emit y = (scan + x*D) * silu(z)
__global__ __launch_bounds__(256) void k_scan_fin(const float* __restrict__ x_act,
                                                  const float* __restrict__ dtb,
                                                  const float* __restrict__ xdbl,
                                                  const float* __restrict__ z_buf,
                                                  const float* __restrict__ A_log,
                                                  const float* __restrict__ Dp,
                                                  const float* __restrict__ s0,
                                                  float* __restrict__ ybuf) {
  __shared__ float Bs[LC][D_STATE];
  __shared__ float Cs[LC][D_STATE];
  const int tid = threadIdx.x;
  const int j = blockIdx.y;
  const int ch = blockIdx.x * 256 + tid;
  const int b = ch >> 11, c = ch & (D_INNER - 1);
  const int t0 = (b << 11) + j * LC;
  {
    int l = tid >> 2, q = (tid & 3) * 4;
    *(float4*)&Bs[l][q] = *(const float4*)&xdbl[(size_t)(t0 + l) * XDBL + DT_RANK + q];
    *(float4*)&Cs[l][q] = *(const float4*)&xdbl[(size_t)(t0 + l) * XDBL + DT_RANK + D_STATE + q];
  }
  float Ar[D_STATE];
#pragma unroll
  for (int n4 = 0; n4 < 4; n4++) {
    float4 a = *(const float4*)&A_log[(size_t)c * D_STATE + n4 * 4];
    Ar[n4 * 4 + 0] = -__expf(a.x); Ar[n4 * 4 + 1] = -__expf(a.y);
    Ar[n4 * 4 + 2] = -__expf(a.z); Ar[n4 * 4 + 3] = -__expf(a.w);
  }
  __syncthreads();
  float st[D_STATE];
  const size_t sb = ((size_t)j * NTOK + ch) * D_STATE;
#pragma unroll
  for (int n4 = 0; n4 < 4; n4++) {
    float4 s = *(const float4*)&s0[sb + n4 * 4];
    st[n4 * 4 + 0] = s.x; st[n4 * 4 + 1] = s.y; st[n4 * 4 + 2] = s.z; st[n4 * 4 + 3] = s.w;
  }
  const float Dc = Dp[c];
  float dtc = dtb[(size_t)t0 * D_INNER + c];
  float xc = x_act[(size_t)t0 * D_INNER + c];
  for (int l = 0; l < LC; l++) {
    float dtn = 0.f, xn = 0.f;
    if (l < LC - 1) {
      dtn = dtb[(size_t)(t0 + l + 1) * D_INNER + c];
      xn = x_act[(size_t)(t0 + l + 1) * D_INNER + c];
    }
    const float zv = z_buf[(size_t)(t0 + l) * D_INNER + c];
    const float dtx = dtc * xc;
    float y = 0.f;
#pragma unroll
    for (int n = 0; n < D_STATE; n++) {
      float dA = __expf(dtc * Ar[n]);
      st[n] = fmaf(st[n], dA, dtx * Bs[l][n]);
      y = fmaf(st[n], Cs[l][n], y);
    }
    float yv = fmaf(xc, Dc, y);
    ybuf[(size_t)(t0 + l) * D_INNER + c] = yv * siluf(zv);
    dtc = dtn; xc = xn;
  }
}

extern "C" void kernel_launch(void* const* d_in, const int* in_sizes, int n_in,
                              void* d_out, int out_size, void* d_ws, size_t ws_size,
                              hipStream_t stream) {
  const float* h = (const float*)d_in[0];
  const int* ids = (const int*)d_in[1];
  const float* Win = (const float*)d_in[2];
  const float* cw = (const float*)d_in[3];
  const float* cb = (const float*)d_in[4];
  const float* Wx = (const float*)d_in[5];
  const float* Wdt = (const float*)d_in[6];
  const float* bdt = (const float*)d_in[7];
  const float* Alog = (const float*)d_in[8];
  const float* Dp = (const float*)d_in[9];
  const float* Wout = (const float*)d_in[10];
  float* out = (float*)d_out;

  const size_t NTD = (size_t)NTOK * D_INNER;  // 8,388,608 floats
  float* ws = (float*)d_ws;
  float* x_act = ws;             // post conv+silu x, token-major
  float* z_buf = ws + NTD;       // z
  float* dtb_p = ws + 2 * NTD;   // softplus(dt)
  float* y_p = ws + 3 * NTD;     // pre-conv x -> F -> y (sequentially dead aliases)
  float* xdbl_p = ws + 4 * NTD;  // NTOK*96
  int* perm = (int*)(ws + 4 * NTD + (size_t)NTOK * XDBL);
  float* x_raw = y_p;
  float* F = y_p;                             // NC*NTOK*16 = 2.1M floats <= NTD
  float* s0 = (float*)d_out;                  // scratch inside d_out (overwritten by out-proj)
  float* Sdt = (float*)d_out + (size_t)NC * NTOK * D_STATE;

  k_perm<<<1, 1024, 0, stream>>>(ids, perm);
  k_gemmT<D_MODEL, D_MODEL, 2 * D_INNER, 0, 1>
      <<<dim3(32, 32), 256, 0, stream>>>(h, perm, ids, Win, nullptr, x_raw, z_buf);
  k_conv<<<NTD / 256, 256, 0, stream>>>(x_raw, cw, cb, x_act);
  k_xdbl<<<NTOK / 4, 512, 0, stream>>>(x_act, ids, Wx, xdbl_p);
  k_gemmT<DT_RANK, XDBL, D_INNER, D_INNER, 2>
      <<<dim3(16, 32), 256, 0, stream>>>(xdbl_p, perm, ids, Wdt, bdt, dtb_p, nullptr);
  k_scan_part<<<dim3(16, NC), 256, 0, stream>>>(x_act, dtb_p, xdbl_p, Alog, F, Sdt);
  k_combine<<<256, 256, 0, stream>>>(F, Sdt, Alog, s0);
  k_scan_fin<<<dim3(16, NC), 256, 0, stream>>>(x_act, dtb_p, xdbl_p, z_buf, Alog, Dp, s0, y_p);
  k_gemmT<D_INNER, D_INNER, D_MODEL, D_MODEL, 0>
      <<<dim3(8, 32), 256, 0, stream>>>(y_p, perm, ids, Wout, nullptr, out, nullptr);
}

// Round 3
// 422.689 us; speedup vs baseline: 8.6658x; 4.7686x over previous
//
#include <hip/hip_runtime.h>
#include <hip/hip_bf16.h>
#include <math.h>

#define B_SZ 2
#define SEQLEN 2048
#define D_MODEL 1024
#define D_INNER 2048
#define D_STATE 16
#define D_CONV 4
#define DT_RANK 64
#define NTOK (B_SZ * SEQLEN)      /* 4096 */
#define XDBL 96                   /* DT_RANK + 2*D_STATE */
#define NC 32                     /* scan chunks */
#define LC 64                     /* chunk length */

typedef float f32x4 __attribute__((ext_vector_type(4)));
typedef unsigned int u32x4 __attribute__((ext_vector_type(4)));
typedef __hip_bfloat16 bf16;

__device__ __forceinline__ float siluf(float v) { return v / (1.f + __expf(-v)); }
__device__ __forceinline__ float softplusf(float v) { return (v > 20.f) ? v : log1pf(__expf(v)); }

__device__ __forceinline__ void mfma_bf16(f32x4& acc, u32x4 a, u32x4 b) {
  // D = A*B + C ; 16x16x32 bf16 : A,B 4 VGPR (8 bf16), C/D 4 VGPR f32
  asm("v_mfma_f32_16x16x32_bf16 %0, %1, %2, %0" : "+v"(acc) : "v"(a), "v"(b));
}

// ---- token partition by expert: perm = [tokens id==0 (stable), tokens id==1]
__global__ __launch_bounds__(1024) void k_perm(const int* __restrict__ ids, int* __restrict__ perm) {
  __shared__ int sc[1024];
  const int tid = threadIdx.x;
  int loc[4];
  int cnt = 0;
#pragma unroll
  for (int q = 0; q < 4; q++) {
    loc[q] = ids[tid * 4 + q];
    cnt += (loc[q] == 0);
  }
  sc[tid] = cnt;
  __syncthreads();
  for (int off = 1; off < 1024; off <<= 1) {
    int v = sc[tid];
    int u = (tid >= off) ? sc[tid - off] : 0;
    __syncthreads();
    sc[tid] = v + u;
    __syncthreads();
  }
  const int N0 = sc[1023];
  int zb = sc[tid] - cnt;
#pragma unroll
  for (int q = 0; q < 4; q++) {
    int t = tid * 4 + q;
    if (loc[q] == 0) { perm[zb] = t; zb++; }
    else             { perm[N0 + (t - zb)] = t; }
  }
}

// ---- fused fp32 -> bf16 conversion of h and all GEMM weights
#define CVT_H   (NTOK * D_MODEL)                 /* 4194304 */
#define CVT_WIN (2 * 2 * D_INNER * D_MODEL)      /* 8388608 */
#define CVT_WX  (2 * XDBL * D_INNER)             /* 393216 */
#define CVT_WDT (2 * D_INNER * DT_RANK)          /* 262144 */
#define CVT_WO  (2 * D_MODEL * D_INNER)          /* 4194304 */
#define CVT_TOT (CVT_H + CVT_WIN + CVT_WX + CVT_WDT + CVT_WO) /* 17432576 */
__global__ __launch_bounds__(256) void k_cvtall(const float* __restrict__ h,
                                                const float* __restrict__ Win,
                                                const float* __restrict__ Wx,
                                                const float* __restrict__ Wdt,
                                                const float* __restrict__ Wout,
                                                bf16* __restrict__ hB, bf16* __restrict__ WinB,
                                                bf16* __restrict__ WxB, bf16* __restrict__ WdtB,
                                                bf16* __restrict__ WoB) {
  size_t i = ((size_t)blockIdx.x * 256 + threadIdx.x) * 8;
  const float* src; bf16* dst; size_t off;
  if (i < CVT_H)                          { src = h;    dst = hB;   off = i; }
  else if (i < CVT_H + CVT_WIN)           { src = Win;  dst = WinB; off = i - CVT_H; }
  else if (i < CVT_H + CVT_WIN + CVT_WX)  { src = Wx;   dst = WxB;  off = i - CVT_H - CVT_WIN; }
  else if (i < CVT_TOT - CVT_WO)          { src = Wdt;  dst = WdtB; off = i - CVT_H - CVT_WIN - CVT_WX; }
  else                                    { src = Wout; dst = WoB;  off = i - (CVT_TOT - CVT_WO); }
  float4 f0 = *(const float4*)&src[off];
  float4 f1 = *(const float4*)&src[off + 4];
  __align__(16) bf16 tmp[8];
  tmp[0] = __float2bfloat16(f0.x); tmp[1] = __float2bfloat16(f0.y);
  tmp[2] = __float2bfloat16(f0.z); tmp[3] = __float2bfloat16(f0.w);
  tmp[4] = __float2bfloat16(f1.x); tmp[5] = __float2bfloat16(f1.y);
  tmp[6] = __float2bfloat16(f1.z); tmp[7] = __float2bfloat16(f1.w);
  *(u32x4*)&dst[off] = *(const u32x4*)tmp;
}

// ---- bf16 MFMA expert-gathered GEMM: out[t][o] = sum_k act[perm-row t][k] * W[id(t)][o][k]
// 128x128 tile, BK=64, 4 waves (2x2), 16x16x32 MFMA. Mixed blocks: 2 passes with
// complement-masked A rows (C = sum_e mask_e(A) * B_e).
// EPI 0: out0[t*LDO+col] fp32
// EPI 1: split col<2048 -> out0 (x_raw), else out1 (z)
// EPI 2: out0 = softplus(acc + bias[e*NW+col])
// EPI 3: col<96 -> out0 fp32 (xdbl); col<64 -> outb bf16 (xdbl64)
template <int KDIM, int NW, int LDO, int EPI>
__global__ __launch_bounds__(256, 2) void k_gemmM(const bf16* __restrict__ actB,
                                                  const int* __restrict__ perm,
                                                  const int* __restrict__ ids,
                                                  const bf16* __restrict__ WB,
                                                  const float* __restrict__ bias,
                                                  float* __restrict__ out0,
                                                  float* __restrict__ out1,
                                                  bf16* __restrict__ outb) {
  constexpr int LDT = 72;  // padded LDS row (bf16 elems): 144B -> 2-way read aliasing (free)
  __shared__ bf16 As[128 * LDT];
  __shared__ bf16 Ws[128 * LDT];
  __shared__ int permL[128];
  __shared__ int eidL[128];
  const int tid = threadIdx.x;
  const int ot = blockIdx.x * 128;
  const int tt = blockIdx.y * 128;
  if (tid < 128) {
    int t = perm[tt + tid];
    permL[tid] = t;
    eidL[tid] = ids[t];
  }
  __syncthreads();
  const int eu = eidL[0];
  const bool mixed = (eidL[127] != eu);

  const int lane = tid & 63, wid = tid >> 6;
  const int wr = wid >> 1, wc = wid & 1;
  const int lr = lane & 15, lg = lane >> 4;

  f32x4 acc[4][4];
#pragma unroll
  for (int i = 0; i < 4; i++)
#pragma unroll
    for (int j = 0; j < 4; j++) acc[i][j] = (f32x4){0.f, 0.f, 0.f, 0.f};

  // per-thread staging slots (4 x 16B for A, same for W), loop-invariant parts
  int arow[4], aoff[4], aeid[4];
  size_t abase[4], bbase[4];
#pragma unroll
  for (int v = 0; v < 4; v++) {
    const int slot = tid * 4 + v;       // 0..1023
    const int row = slot >> 3;          // 0..127
    const int k8 = slot & 7;            // 8-elem column group
    arow[v] = row;
    aoff[v] = row * LDT + k8 * 8;
    aeid[v] = eidL[row];
    abase[v] = (size_t)permL[row] * KDIM + k8 * 8;
    int orow = ot + row;
    if (NW % 128 != 0) orow = (orow < NW) ? orow : (NW - 1);
    bbase[v] = (size_t)orow * KDIM + k8 * 8;
  }

  const int npass = mixed ? 2 : 1;
  for (int ps = 0; ps < npass; ++ps) {
    const int e = ps ? (1 - eu) : eu;
    const size_t wexp = (size_t)e * NW * KDIM;
    for (int k0 = 0; k0 < KDIM; k0 += 64) {
#pragma unroll
      for (int v = 0; v < 4; v++) {
        u32x4 va = *(const u32x4*)&actB[abase[v] + k0];
        if (mixed && aeid[v] != e) va = (u32x4){0u, 0u, 0u, 0u};
        u32x4 vb = *(const u32x4*)&WB[wexp + bbase[v] + k0];
        *(u32x4*)&As[aoff[v]] = va;
        *(u32x4*)&Ws[aoff[v]] = vb;
      }
      __syncthreads();
#pragma unroll
      for (int ks = 0; ks < 64; ks += 32) {
        u32x4 a[4], b[4];
#pragma unroll
        for (int f = 0; f < 4; f++)
          a[f] = *(const u32x4*)&As[(wr * 64 + f * 16 + lr) * LDT + ks + lg * 8];
#pragma unroll
        for (int f = 0; f < 4; f++)
          b[f] = *(const u32x4*)&Ws[(wc * 64 + f * 16 + lr) * LDT + ks + lg * 8];
#pragma unroll
        for (int i = 0; i < 4; i++)
#pragma unroll
          for (int j = 0; j < 4; j++) mfma_bf16(acc[i][j], a[i], b[j]);
      }
      __syncthreads();
    }
  }

  // epilogue: C row = lg*4 + r (within 16), col = lr
#pragma unroll
  for (int i = 0; i < 4; i++) {
#pragma unroll
    for (int r = 0; r < 4; r++) {
      const int m = wr * 64 + i * 16 + lg * 4 + r;
      const int t = permL[m];
#pragma unroll
      for (int j = 0; j < 4; j++) {
        const int col = ot + wc * 64 + j * 16 + lr;
        float v = acc[i][j][r];
        if (EPI == 0) {
          out0[(size_t)t * LDO + col] = v;
        } else if (EPI == 1) {
          if (col < D_INNER) out0[(size_t)t * D_INNER + col] = v;
          else out1[(size_t)t * D_INNER + (col - D_INNER)] = v;
        } else if (EPI == 2) {
          v = softplusf(v + bias[eidL[m] * NW + col]);
          out0[(size_t)t * LDO + col] = v;
        } else {
          if (col < XDBL) out0[(size_t)t * XDBL + col] = v;
          if (col < DT_RANK) outb[(size_t)t * DT_RANK + col] = __float2bfloat16(v);
        }
      }
    }
  }
}

// ---- depthwise causal conv + SiLU; emits fp32 x_act and bf16 xB
__global__ __launch_bounds__(256) void k_conv(const float* __restrict__ x_raw,
                                              const float* __restrict__ cw,
                                              const float* __restrict__ cb,
                                              float* __restrict__ x_act,
                                              bf16* __restrict__ xB) {
  int idx = blockIdx.x * 256 + threadIdx.x;
  int c = idx & (D_INNER - 1);
  int t = idx >> 11;
  int l = t & (SEQLEN - 1);
  int b = t >> 11;
  float acc = cb[c];
#pragma unroll
  for (int k = 0; k < D_CONV; k++) {
    int ll = l + k - (D_CONV - 1);
    if (ll >= 0)
      acc = fmaf(cw[c * D_CONV + k], x_raw[((size_t)(b * SEQLEN + ll)) * D_INNER + c], acc);
  }
  float s = siluf(acc);
  x_act[(size_t)idx] = s;
  xB[(size_t)idx] = __float2bfloat16(s);
}

// ---- scan pass A: per-chunk local scan -> F, Sdt
__global__ __launch_bounds__(256) void k_scan_part(const float* __restrict__ x_act,
                                                   const float* __restrict__ dtb,
                                                   const float* __restrict__ xdbl,
                                                   const float* __restrict__ A_log,
                                                   float* __restrict__ F,
                                                   float* __restrict__ Sdt) {
  __shared__ float Bs[LC][D_STATE];
  const int tid = threadIdx.x;
  const int j = blockIdx.y;
  const int ch = blockIdx.x * 256 + tid;
  const int b = ch >> 11, c = ch & (D_INNER - 1);
  const int t0 = (b << 11) + j * LC;
  {
    int l = tid >> 2, q = (tid & 3) * 4;
    *(float4*)&Bs[l][q] = *(const float4*)&xdbl[(size_t)(t0 + l) * XDBL + DT_RANK + q];
  }
  float Ar[D_STATE];
#pragma unroll
  for (int n4 = 0; n4 < 4; n4++) {
    float4 a = *(const float4*)&A_log[(size_t)c * D_STATE + n4 * 4];
    Ar[n4 * 4 + 0] = -__expf(a.x); Ar[n4 * 4 + 1] = -__expf(a.y);
    Ar[n4 * 4 + 2] = -__expf(a.z); Ar[n4 * 4 + 3] = -__expf(a.w);
  }
  __syncthreads();
  float st[D_STATE];
#pragma unroll
  for (int n = 0; n < D_STATE; n++) st[n] = 0.f;
  float sdt = 0.f;
  float dtc = dtb[(size_t)t0 * D_INNER + c];
  float xc = x_act[(size_t)t0 * D_INNER + c];
  for (int l = 0; l < LC; l++) {
    float dtn = 0.f, xn = 0.f;
    if (l < LC - 1) {
      dtn = dtb[(size_t)(t0 + l + 1) * D_INNER + c];
      xn = x_act[(size_t)(t0 + l + 1) * D_INNER + c];
    }
    const float dtx = dtc * xc;
    sdt += dtc;
#pragma unroll
    for (int n = 0; n < D_STATE; n++) {
      float dA = __expf(dtc * Ar[n]);
      st[n] = fmaf(st[n], dA, dtx * Bs[l][n]);
    }
    dtc = dtn; xc = xn;
  }
  const size_t fb = ((size_t)j * NTOK + ch) * D_STATE;
#pragma unroll
  for (int n4 = 0; n4 < 4; n4++)
    *(float4*)&F[fb + n4 * 4] = make_float4(st[n4 * 4], st[n4 * 4 + 1], st[n4 * 4 + 2], st[n4 * 4 + 3]);
  Sdt[(size_t)j * NTOK + ch] = sdt;
}

// ---- scan pass B: sequential combine across chunks -> s0 per chunk
__global__ __launch_bounds__(256) void k_combine(const float* __restrict__ F,
                                                 const float* __restrict__ Sdt,
                                                 const float* __restrict__ A_log,
                                                 float* __restrict__ s0) {
  const int gid = blockIdx.x * 256 + threadIdx.x;
  const int ch = gid >> 4, n = gid & 15, c = ch & (D_INNER - 1);
  const float Ar = -__expf(A_log[(size_t)c * D_STATE + n]);
  float s = 0.f;
  for (int j = 0; j < NC; j++) {
    s0[((size_t)j * NTOK + ch) * D_STATE + n] = s;
    s = fmaf(s, __expf(Ar * Sdt[(size_t)j * NTOK + ch]), F[((size_t)j * NTOK + ch) * D_STATE + n]);
  }
}

// ---- scan pass C: recompute with s0, emit yB = bf16((scan + x*D) * silu(z))
__global__ __launch_bounds__(256) void k_scan_fin(const float* __restrict__ x_act,
                                                  const float* __restrict__ dtb,
                                                  const float* __restrict__ xdbl,
                                                  const float* __restrict__ z_buf,
                                                  const float* __restrict__ A_log,
                                                  const float* __restrict__ Dp,
                                                  const float* __restrict__ s0,
                                                  bf16* __restrict__ ybuf) {
  __shared__ float Bs[LC][D_STATE];
  __shared__ float Cs[LC][D_STATE];
  const int tid = threadIdx.x;
  const int j = blockIdx.y;
  const int ch = blockIdx.x * 256 + tid;
  const int b = ch >> 11, c = ch & (D_INNER - 1);
  const int t0 = (b << 11) + j * LC;
  {
    int l = tid >> 2, q = (tid & 3) * 4;
    *(float4*)&Bs[l][q] = *(const float4*)&xdbl[(size_t)(t0 + l) * XDBL + DT_RANK + q];
    *(float4*)&Cs[l][q] = *(const float4*)&xdbl[(size_t)(t0 + l) * XDBL + DT_RANK + D_STATE + q];
  }
  float Ar[D_STATE];
#pragma unroll
  for (int n4 = 0; n4 < 4; n4++) {
    float4 a = *(const float4*)&A_log[(size_t)c * D_STATE + n4 * 4];
    Ar[n4 * 4 + 0] = -__expf(a.x); Ar[n4 * 4 + 1] = -__expf(a.y);
    Ar[n4 * 4 + 2] = -__expf(a.z); Ar[n4 * 4 + 3] = -__expf(a.w);
  }
  __syncthreads();
  float st[D_STATE];
  const size_t sb = ((size_t)j * NTOK + ch) * D_STATE;
#pragma unroll
  for (int n4 = 0; n4 < 4; n4++) {
    float4 s = *(const float4*)&s0[sb + n4 * 4];
    st[n4 * 4 + 0] = s.x; st[n4 * 4 + 1] = s.y; st[n4 * 4 + 2] = s.z; st[n4 * 4 + 3] = s.w;
  }
  const float Dc = Dp[c];
  float dtc = dtb[(size_t)t0 * D_INNER + c];
  float xc = x_act[(size_t)t0 * D_INNER + c];
  for (int l = 0; l < LC; l++) {
    float dtn = 0.f, xn = 0.f;
    if (l < LC - 1) {
      dtn = dtb[(size_t)(t0 + l + 1) * D_INNER + c];
      xn = x_act[(size_t)(t0 + l + 1) * D_INNER + c];
    }
    const float zv = z_buf[(size_t)(t0 + l) * D_INNER + c];
    const float dtx = dtc * xc;
    float y = 0.f;
#pragma unroll
    for (int n = 0; n < D_STATE; n++) {
      float dA = __expf(dtc * Ar[n]);
      st[n] = fmaf(st[n], dA, dtx * Bs[l][n]);
      y = fmaf(st[n], Cs[l][n], y);
    }
    float yv = fmaf(xc, Dc, y);
    ybuf[(size_t)(t0 + l) * D_INNER + c] = __float2bfloat16(yv * siluf(zv));
    dtc = dtn; xc = xn;
  }
}

extern "C" void kernel_launch(void* const* d_in, const int* in_sizes, int n_in,
                              void* d_out, int out_size, void* d_ws, size_t ws_size,
                              hipStream_t stream) {
  const float* h = (const float*)d_in[0];
  const int* ids = (const int*)d_in[1];
  const float* Win = (const float*)d_in[2];
  const float* cw = (const float*)d_in[3];
  const float* cb = (const float*)d_in[4];
  const float* Wx = (const float*)d_in[5];
  const float* Wdt = (const float*)d_in[6];
  const float* bdt = (const float*)d_in[7];
  const float* Alog = (const float*)d_in[8];
  const float* Dp = (const float*)d_in[9];
  const float* Wout = (const float*)d_in[10];
  float* out = (float*)d_out;

  const size_t NTD = (size_t)NTOK * D_INNER;  // 8,388,608
  float* ws = (float*)d_ws;
  float* x_act = ws + 0 * NTD;   // fp32 x_act; hosts hB (bf16, 8.4MB) before conv
  float* z_buf = ws + 1 * NTD;
  float* dtb_p = ws + 2 * NTD;   // fp32 dt; hosts WinB (bf16, 16.8MB) before dt-GEMM
  float* xraw_p = ws + 3 * NTD;  // fp32 pre-conv x -> F (8.4MB) -> yB (bf16 16.8MB)
  size_t cur = 4 * NTD;
  float* xdbl_p = ws + cur; cur += (size_t)NTOK * XDBL;   // 393216
  float* sdt_p = ws + cur; cur += (size_t)NC * NTOK;      // 131072
  int* perm = (int*)(ws + cur); cur += NTOK;              // 4096
  bf16* xB = (bf16*)(ws + cur); cur += NTD / 2;           // bf16 x for x-proj
  bf16* WoB = (bf16*)(ws + cur); cur += CVT_WO / 2;
  bf16* WxB = (bf16*)(ws + cur); cur += CVT_WX / 2;
  bf16* WdtB = (bf16*)(ws + cur); cur += CVT_WDT / 2;
  bf16* x64B = (bf16*)(ws + cur); cur += (size_t)NTOK * DT_RANK / 2;

  bf16* hB = (bf16*)x_act;       // alias: dead after in-proj
  bf16* WinB = (bf16*)dtb_p;     // alias: dead after in-proj
  float* F = xraw_p;             // alias: x_raw dead after conv
  bf16* yB = (bf16*)xraw_p;      // alias: F dead after combine
  float* s0 = (float*)d_out;     // scratch in d_out, overwritten by out-proj

  k_perm<<<1, 1024, 0, stream>>>(ids, perm);
  k_cvtall<<<CVT_TOT / 8 / 256, 256, 0, stream>>>(h, Win, Wx, Wdt, Wout, hB, WinB, WxB, WdtB, WoB);
  k_gemmM<D_MODEL, 2 * D_INNER, 0, 1>
      <<<dim3(32, 32), 256, 0, stream>>>(hB, perm, ids, WinB, nullptr, xraw_p, z_buf, nullptr);
  k_conv<<<NTD / 256, 256, 0, stream>>>(xraw_p, cw, cb, x_act, xB);
  k_gemmM<D_INNER, XDBL, XDBL, 3>
      <<<dim3(1, 32), 256, 0, stream>>>(xB, perm, ids, WxB, nullptr, xdbl_p, nullptr, x64B);
  k_gemmM<DT_RANK, D_INNER, D_INNER, 2>
      <<<dim3(16, 32), 256, 0, stream>>>(x64B, perm, ids, WdtB, bdt, dtb_p, nullptr, nullptr);
  k_scan_part<<<dim3(16, NC), 256, 0, stream>>>(x_act, dtb_p, xdbl_p, Alog, F, sdt_p);
  k_combine<<<256, 256, 0, stream>>>(F, sdt_p, Alog, s0);
  k_scan_fin<<<dim3(16, NC), 256, 0, stream>>>(x_act, dtb_p, xdbl_p, z_buf, Alog, Dp, s0, yB);
  k_gemmM<D_INNER, D_MODEL, D_MODEL, 0>
      <<<dim3(8, 32), 256, 0, stream>>>(yB, perm, ids, WoB, nullptr, out, nullptr, nullptr);
}

// Round 4
// 361.655 us; speedup vs baseline: 10.1283x; 1.1688x over previous
//
#include <hip/hip_runtime.h>
#include <hip/hip_bf16.h>
#include <math.h>

#define B_SZ 2
#define SEQLEN 2048
#define D_MODEL 1024
#define D_INNER 2048
#define D_STATE 16
#define D_CONV 4
#define DT_RANK 64
#define NTOK (B_SZ * SEQLEN)      /* 4096 */
#define XDBL 96                   /* DT_RANK + 2*D_STATE */
#define NC 32                     /* scan chunks */
#define LC 64                     /* chunk length */
#define PADTOT (33 * 128)         /* padded perm length */

typedef float f32x4 __attribute__((ext_vector_type(4)));
typedef unsigned int u32x4 __attribute__((ext_vector_type(4)));
typedef __hip_bfloat16 bf16;

__device__ __forceinline__ float siluf(float v) { return v / (1.f + __expf(-v)); }
__device__ __forceinline__ float softplusf(float v) { return (v > 20.f) ? v : log1pf(__expf(v)); }

__device__ __forceinline__ void mfma_bf16(f32x4& acc, u32x4 a, u32x4 b) {
  asm("v_mfma_f32_16x16x32_bf16 %0, %1, %2, %0" : "+v"(acc) : "v"(a), "v"(b));
}

// async global->LDS, 16B per lane; LDS dest is wave-uniform base + lane*16
__device__ __forceinline__ void gload16(const bf16* g, bf16* l) {
  __builtin_amdgcn_global_load_lds(
      (const __attribute__((address_space(1))) unsigned int*)g,
      (__attribute__((address_space(3))) unsigned int*)l, 16, 0, 0);
}

// ---- token partition by expert, padded so every 128-row block is pure-expert.
// perm[0..N0) = expert0 tokens, [N0..m0) = -1, [m0..m0+N1) = expert1, rest -1.
__global__ __launch_bounds__(1024) void k_perm(const int* __restrict__ ids, int* __restrict__ perm) {
  __shared__ int sc[1024];
  const int tid = threadIdx.x;
  int loc[4];
  int cnt = 0;
#pragma unroll
  for (int q = 0; q < 4; q++) {
    loc[q] = ids[tid * 4 + q];
    cnt += (loc[q] == 0);
  }
  sc[tid] = cnt;
  __syncthreads();
  for (int off = 1; off < 1024; off <<= 1) {
    int v = sc[tid];
    int u = (tid >= off) ? sc[tid - off] : 0;
    __syncthreads();
    sc[tid] = v + u;
    __syncthreads();
  }
  const int N0 = sc[1023];
  const int m0 = (N0 + 127) & ~127;
  const int N1 = NTOK - N0;
  for (int idx = tid; idx < PADTOT; idx += 1024)
    if ((idx >= N0 && idx < m0) || idx >= m0 + N1) perm[idx] = -1;
  int zb = sc[tid] - cnt;
#pragma unroll
  for (int q = 0; q < 4; q++) {
    int t = tid * 4 + q;
    if (loc[q] == 0) { perm[zb] = t; zb++; }
    else             { perm[m0 + (t - zb)] = t; }
  }
}

// ---- fused fp32 -> bf16 conversion of h and all GEMM weights
#define CVT_H   (NTOK * D_MODEL)                 /* 4194304 */
#define CVT_WIN (2 * 2 * D_INNER * D_MODEL)      /* 8388608 */
#define CVT_WX  (2 * XDBL * D_INNER)             /* 393216 */
#define CVT_WDT (2 * D_INNER * DT_RANK)          /* 262144 */
#define CVT_WO  (2 * D_MODEL * D_INNER)          /* 4194304 */
#define CVT_TOT (CVT_H + CVT_WIN + CVT_WX + CVT_WDT + CVT_WO) /* 17432576 */
__global__ __launch_bounds__(256) void k_cvtall(const float* __restrict__ h,
                                                const float* __restrict__ Win,
                                                const float* __restrict__ Wx,
                                                const float* __restrict__ Wdt,
                                                const float* __restrict__ Wout,
                                                bf16* __restrict__ hB, bf16* __restrict__ WinB,
                                                bf16* __restrict__ WxB, bf16* __restrict__ WdtB,
                                                bf16* __restrict__ WoB) {
  size_t i = ((size_t)blockIdx.x * 256 + threadIdx.x) * 8;
  const float* src; bf16* dst; size_t off;
  if (i < CVT_H)                          { src = h;    dst = hB;   off = i; }
  else if (i < CVT_H + CVT_WIN)           { src = Win;  dst = WinB; off = i - CVT_H; }
  else if (i < CVT_H + CVT_WIN + CVT_WX)  { src = Wx;   dst = WxB;  off = i - CVT_H - CVT_WIN; }
  else if (i < CVT_TOT - CVT_WO)          { src = Wdt;  dst = WdtB; off = i - CVT_H - CVT_WIN - CVT_WX; }
  else                                    { src = Wout; dst = WoB;  off = i - (CVT_TOT - CVT_WO); }
  float4 f0 = *(const float4*)&src[off];
  float4 f1 = *(const float4*)&src[off + 4];
  __align__(16) bf16 tmp[8];
  tmp[0] = __float2bfloat16(f0.x); tmp[1] = __float2bfloat16(f0.y);
  tmp[2] = __float2bfloat16(f0.z); tmp[3] = __float2bfloat16(f0.w);
  tmp[4] = __float2bfloat16(f1.x); tmp[5] = __float2bfloat16(f1.y);
  tmp[6] = __float2bfloat16(f1.z); tmp[7] = __float2bfloat16(f1.w);
  *(u32x4*)&dst[off] = *(const u32x4*)tmp;
}

// ---- bf16 MFMA expert-gathered GEMM, m97 structure:
// 128x128 tile, BK=64, 4 waves 2x2, global_load_lds width=16, linear LDS.
// Blocks are pure-expert by construction (padded perm); sentinel rows skipped at store.
// EPI 0: out0[t*LDO+col] fp32
// EPI 1: split col<2048 -> out0 (x_raw), else out1 (z)
// EPI 2: out0 = softplus(acc + bias[e*NW+col])
// EPI 3: col<96 -> out0 fp32 (xdbl); col<64 -> outb bf16
template <int KDIM, int NW, int LDO, int EPI>
__global__ __launch_bounds__(256) void k_gemmG(const bf16* __restrict__ actB,
                                               const int* __restrict__ perm,
                                               const int* __restrict__ ids,
                                               const bf16* __restrict__ WB,
                                               const float* __restrict__ bias,
                                               float* __restrict__ out0,
                                               float* __restrict__ out1,
                                               bf16* __restrict__ outb) {
  __shared__ bf16 As[128 * 64];
  __shared__ bf16 Ws[128 * 64];
  __shared__ int permL[128];
  const int tid = threadIdx.x;
  const int ot = blockIdx.x * 128;
  const int tt = blockIdx.y * 128;
  if (tid < 128) permL[tid] = perm[tt + tid];

  const int lane = tid & 63, w = tid >> 6;
  const int wr = w >> 1, wc = w & 1;
  const int lr = lane & 15, lg = lane >> 4;

  const int t00 = perm[tt];
  const int eu = (t00 >= 0) ? ids[t00] : 0;
  const size_t wexp = (size_t)eu * NW * KDIM;

  // staging: wave w covers rows [w*32, w*32+32); instr v covers 8 rows.
  const int srow = w * 32 + (lane >> 3);
  const int scol = (lane & 7) * 8;
  size_t abase[4], bbase[4];
  int ldsoff[4];
#pragma unroll
  for (int v = 0; v < 4; v++) {
    const int row = srow + v * 8;
    int ta = perm[tt + row];
    if (ta < 0) ta = 0;
    abase[v] = (size_t)ta * KDIM + scol;
    int orow = ot + row;
    if (NW % 128 != 0) orow = (orow < NW) ? orow : (NW - 1);
    bbase[v] = wexp + (size_t)orow * KDIM + scol;
    ldsoff[v] = (w * 32 + v * 8) * 64;  // wave-uniform LDS base
  }

  f32x4 acc[4][4];
#pragma unroll
  for (int i = 0; i < 4; i++)
#pragma unroll
    for (int j = 0; j < 4; j++) acc[i][j] = (f32x4){0.f, 0.f, 0.f, 0.f};

  for (int k0 = 0; k0 < KDIM; k0 += 64) {
#pragma unroll
    for (int v = 0; v < 4; v++) {
      gload16(&actB[abase[v] + k0], &As[ldsoff[v]]);
      gload16(&WB[bbase[v] + k0], &Ws[ldsoff[v]]);
    }
    __syncthreads();  // drains vmcnt (global_load_lds) + lgkm
#pragma unroll
    for (int ks = 0; ks < 64; ks += 32) {
      u32x4 a[4], b[4];
#pragma unroll
      for (int f = 0; f < 4; f++)
        a[f] = *(const u32x4*)&As[(wr * 64 + f * 16 + lr) * 64 + ks + lg * 8];
#pragma unroll
      for (int f = 0; f < 4; f++)
        b[f] = *(const u32x4*)&Ws[(wc * 64 + f * 16 + lr) * 64 + ks + lg * 8];
#pragma unroll
      for (int i = 0; i < 4; i++)
#pragma unroll
        for (int j = 0; j < 4; j++) mfma_bf16(acc[i][j], a[i], b[j]);
    }
    __syncthreads();
  }

  // epilogue: C row = lg*4 + r (within 16), col = lr
#pragma unroll
  for (int i = 0; i < 4; i++) {
#pragma unroll
    for (int r = 0; r < 4; r++) {
      const int m = wr * 64 + i * 16 + lg * 4 + r;
      const int t = permL[m];
      if (t < 0) continue;
#pragma unroll
      for (int j = 0; j < 4; j++) {
        const int col = ot + wc * 64 + j * 16 + lr;
        float v = acc[i][j][r];
        if (EPI == 0) {
          out0[(size_t)t * LDO + col] = v;
        } else if (EPI == 1) {
          if (col < D_INNER) out0[(size_t)t * D_INNER + col] = v;
          else out1[(size_t)t * D_INNER + (col - D_INNER)] = v;
        } else if (EPI == 2) {
          v = softplusf(v + bias[eu * NW + col]);
          out0[(size_t)t * LDO + col] = v;
        } else {
          if (col < XDBL) out0[(size_t)t * XDBL + col] = v;
          if (col < DT_RANK) outb[(size_t)t * DT_RANK + col] = __float2bfloat16(v);
        }
      }
    }
  }
}

// ---- depthwise causal conv + SiLU; emits fp32 x_act and bf16 xB
__global__ __launch_bounds__(256) void k_conv(const float* __restrict__ x_raw,
                                              const float* __restrict__ cw,
                                              const float* __restrict__ cb,
                                              float* __restrict__ x_act,
                                              bf16* __restrict__ xB) {
  int idx = blockIdx.x * 256 + threadIdx.x;
  int c = idx & (D_INNER - 1);
  int t = idx >> 11;
  int l = t & (SEQLEN - 1);
  int b = t >> 11;
  float acc = cb[c];
#pragma unroll
  for (int k = 0; k < D_CONV; k++) {
    int ll = l + k - (D_CONV - 1);
    if (ll >= 0)
      acc = fmaf(cw[c * D_CONV + k], x_raw[((size_t)(b * SEQLEN + ll)) * D_INNER + c], acc);
  }
  float s = siluf(acc);
  x_act[(size_t)idx] = s;
  xB[(size_t)idx] = __float2bfloat16(s);
}

// ---- scan pass A: per-chunk local scan -> F, Sdt
__global__ __launch_bounds__(256) void k_scan_part(const float* __restrict__ x_act,
                                                   const float* __restrict__ dtb,
                                                   const float* __restrict__ xdbl,
                                                   const float* __restrict__ A_log,
                                                   float* __restrict__ F,
                                                   float* __restrict__ Sdt) {
  __shared__ float Bs[LC][D_STATE];
  const int tid = threadIdx.x;
  const int j = blockIdx.y;
  const int ch = blockIdx.x * 256 + tid;
  const int b = ch >> 11, c = ch & (D_INNER - 1);
  const int t0 = (b << 11) + j * LC;
  {
    int l = tid >> 2, q = (tid & 3) * 4;
    *(float4*)&Bs[l][q] = *(const float4*)&xdbl[(size_t)(t0 + l) * XDBL + DT_RANK + q];
  }
  float Ar[D_STATE];
#pragma unroll
  for (int n4 = 0; n4 < 4; n4++) {
    float4 a = *(const float4*)&A_log[(size_t)c * D_STATE + n4 * 4];
    Ar[n4 * 4 + 0] = -__expf(a.x); Ar[n4 * 4 + 1] = -__expf(a.y);
    Ar[n4 * 4 + 2] = -__expf(a.z); Ar[n4 * 4 + 3] = -__expf(a.w);
  }
  __syncthreads();
  float st[D_STATE];
#pragma unroll
  for (int n = 0; n < D_STATE; n++) st[n] = 0.f;
  float sdt = 0.f;
  float dtc = dtb[(size_t)t0 * D_INNER + c];
  float xc = x_act[(size_t)t0 * D_INNER + c];
  for (int l = 0; l < LC; l++) {
    float dtn = 0.f, xn = 0.f;
    if (l < LC - 1) {
      dtn = dtb[(size_t)(t0 + l + 1) * D_INNER + c];
      xn = x_act[(size_t)(t0 + l + 1) * D_INNER + c];
    }
    const float dtx = dtc * xc;
    sdt += dtc;
#pragma unroll
    for (int n = 0; n < D_STATE; n++) {
      float dA = __expf(dtc * Ar[n]);
      st[n] = fmaf(st[n], dA, dtx * Bs[l][n]);
    }
    dtc = dtn; xc = xn;
  }
  const size_t fb = ((size_t)j * NTOK + ch) * D_STATE;
#pragma unroll
  for (int n4 = 0; n4 < 4; n4++)
    *(float4*)&F[fb + n4 * 4] = make_float4(st[n4 * 4], st[n4 * 4 + 1], st[n4 * 4 + 2], st[n4 * 4 + 3]);
  Sdt[(size_t)j * NTOK + ch] = sdt;
}

// ---- scan pass B: sequential combine across chunks -> s0 per chunk
__global__ __launch_bounds__(256) void k_combine(const float* __restrict__ F,
                                                 const float* __restrict__ Sdt,
                                                 const float* __restrict__ A_log,
                                                 float* __restrict__ s0) {
  const int gid = blockIdx.x * 256 + threadIdx.x;
  const int ch = gid >> 4, n = gid & 15, c = ch & (D_INNER - 1);
  const float Ar = -__expf(A_log[(size_t)c * D_STATE + n]);
  float s = 0.f;
  for (int j = 0; j < NC; j++) {
    s0[((size_t)j * NTOK + ch) * D_STATE + n] = s;
    s = fmaf(s, __expf(Ar * Sdt[(size_t)j * NTOK + ch]), F[((size_t)j * NTOK + ch) * D_STATE + n]);
  }
}

// ---- scan pass C: recompute with s0, emit yB = bf16((scan + x*D) * silu(z))
__global__ __launch_bounds__(256) void k_scan_fin(const float* __restrict__ x_act,
                                                  const float* __restrict__ dtb,
                                                  const float* __restrict__ xdbl,
                                                  const float* __restrict__ z_buf,
                                                  const float* __restrict__ A_log,
                                                  const float* __restrict__ Dp,
                                                  const float* __restrict__ s0,
                                                  bf16* __restrict__ ybuf) {
  __shared__ float Bs[LC][D_STATE];
  __shared__ float Cs[LC][D_STATE];
  const int tid = threadIdx.x;
  const int j = blockIdx.y;
  const int ch = blockIdx.x * 256 + tid;
  const int b = ch >> 11, c = ch & (D_INNER - 1);
  const int t0 = (b << 11) + j * LC;
  {
    int l = tid >> 2, q = (tid & 3) * 4;
    *(float4*)&Bs[l][q] = *(const float4*)&xdbl[(size_t)(t0 + l) * XDBL + DT_RANK + q];
    *(float4*)&Cs[l][q] = *(const float4*)&xdbl[(size_t)(t0 + l) * XDBL + DT_RANK + D_STATE + q];
  }
  float Ar[D_STATE];
#pragma unroll
  for (int n4 = 0; n4 < 4; n4++) {
    float4 a = *(const float4*)&A_log[(size_t)c * D_STATE + n4 * 4];
    Ar[n4 * 4 + 0] = -__expf(a.x); Ar[n4 * 4 + 1] = -__expf(a.y);
    Ar[n4 * 4 + 2] = -__expf(a.z); Ar[n4 * 4 + 3] = -__expf(a.w);
  }
  __syncthreads();
  float st[D_STATE];
  const size_t sb = ((size_t)j * NTOK + ch) * D_STATE;
#pragma unroll
  for (int n4 = 0; n4 < 4; n4++) {
    float4 s = *(const float4*)&s0[sb + n4 * 4];
    st[n4 * 4 + 0] = s.x; st[n4 * 4 + 1] = s.y; st[n4 * 4 + 2] = s.z; st[n4 * 4 + 3] = s.w;
  }
  const float Dc = Dp[c];
  float dtc = dtb[(size_t)t0 * D_INNER + c];
  float xc = x_act[(size_t)t0 * D_INNER + c];
  for (int l = 0; l < LC; l++) {
    float dtn = 0.f, xn = 0.f;
    if (l < LC - 1) {
      dtn = dtb[(size_t)(t0 + l + 1) * D_INNER + c];
      xn = x_act[(size_t)(t0 + l + 1) * D_INNER + c];
    }
    const float zv = z_buf[(size_t)(t0 + l) * D_INNER + c];
    const float dtx = dtc * xc;
    float y = 0.f;
#pragma unroll
    for (int n = 0; n < D_STATE; n++) {
      float dA = __expf(dtc * Ar[n]);
      st[n] = fmaf(st[n], dA, dtx * Bs[l][n]);
      y = fmaf(st[n], Cs[l][n], y);
    }
    float yv = fmaf(xc, Dc, y);
    ybuf[(size_t)(t0 + l) * D_INNER + c] = __float2bfloat16(yv * siluf(zv));
    dtc = dtn; xc = xn;
  }
}

extern "C" void kernel_launch(void* const* d_in, const int* in_sizes, int n_in,
                              void* d_out, int out_size, void* d_ws, size_t ws_size,
                              hipStream_t stream) {
  const float* h = (const float*)d_in[0];
  const int* ids = (const int*)d_in[1];
  const float* Win = (const float*)d_in[2];
  const float* cw = (const float*)d_in[3];
  const float* cb = (const float*)d_in[4];
  const float* Wx = (const float*)d_in[5];
  const float* Wdt = (const float*)d_in[6];
  const float* bdt = (const float*)d_in[7];
  const float* Alog = (const float*)d_in[8];
  const float* Dp = (const float*)d_in[9];
  const float* Wout = (const float*)d_in[10];
  float* out = (float*)d_out;

  const size_t NTD = (size_t)NTOK * D_INNER;  // 8,388,608
  float* ws = (float*)d_ws;
  float* x_act = ws + 0 * NTD;   // fp32 x_act; hosts hB (bf16) before conv
  float* z_buf = ws + 1 * NTD;
  float* dtb_p = ws + 2 * NTD;   // fp32 dt; hosts WinB (bf16) before dt-GEMM
  float* xraw_p = ws + 3 * NTD;  // fp32 pre-conv x -> F -> yB (aliased, sequentially dead)
  size_t cur = 4 * NTD;
  float* xdbl_p = ws + cur; cur += (size_t)NTOK * XDBL;
  float* sdt_p = ws + cur; cur += (size_t)NC * NTOK;
  int* perm = (int*)(ws + cur); cur += PADTOT;
  bf16* xB = (bf16*)(ws + cur); cur += NTD / 2;
  bf16* WoB = (bf16*)(ws + cur); cur += CVT_WO / 2;
  bf16* WxB = (bf16*)(ws + cur); cur += CVT_WX / 2;
  bf16* WdtB = (bf16*)(ws + cur); cur += CVT_WDT / 2;
  bf16* x64B = (bf16*)(ws + cur); cur += (size_t)NTOK * DT_RANK / 2;

  bf16* hB = (bf16*)x_act;
  bf16* WinB = (bf16*)dtb_p;
  float* F = xraw_p;
  bf16* yB = (bf16*)xraw_p;
  float* s0 = (float*)d_out;  // scratch in d_out, fully overwritten by out-proj

  k_perm<<<1, 1024, 0, stream>>>(ids, perm);
  k_cvtall<<<CVT_TOT / 8 / 256, 256, 0, stream>>>(h, Win, Wx, Wdt, Wout, hB, WinB, WxB, WdtB, WoB);
  k_gemmG<D_MODEL, 2 * D_INNER, 0, 1>
      <<<dim3(32, 33), 256, 0, stream>>>(hB, perm, ids, WinB, nullptr, xraw_p, z_buf, nullptr);
  k_conv<<<NTD / 256, 256, 0, stream>>>(xraw_p, cw, cb, x_act, xB);
  k_gemmG<D_INNER, XDBL, XDBL, 3>
      <<<dim3(1, 33), 256, 0, stream>>>(xB, perm, ids, WxB, nullptr, xdbl_p, nullptr, x64B);
  k_gemmG<DT_RANK, D_INNER, D_INNER, 2>
      <<<dim3(16, 33), 256, 0, stream>>>(x64B, perm, ids, WdtB, bdt, dtb_p, nullptr, nullptr);
  k_scan_part<<<dim3(16, NC), 256, 0, stream>>>(x_act, dtb_p, xdbl_p, Alog, F, sdt_p);
  k_combine<<<256, 256, 0, stream>>>(F, sdt_p, Alog, s0);
  k_scan_fin<<<dim3(16, NC), 256, 0, stream>>>(x_act, dtb_p, xdbl_p, z_buf, Alog, Dp, s0, yB);
  k_gemmG<D_INNER, D_MODEL, D_MODEL, 0>
      <<<dim3(8, 33), 256, 0, stream>>>(yB, perm, ids, WoB, nullptr, out, nullptr, nullptr);
}